// Round 6
// baseline (938.911 us; speedup 1.0000x reference)
//
#include <hip/hip_runtime.h>

#define TT 512
#define DD 64
#define BB 1024
#define PF 8               // prefetch depth (steps) in the recurrence
#define HH 8

typedef float v2f __attribute__((ext_vector_type(2)));

__device__ __forceinline__ float fexp2(float x){ return __builtin_amdgcn_exp2f(x); }
__device__ __forceinline__ float frcp (float x){ return __builtin_amdgcn_rcpf(x); }

__device__ __forceinline__ v2f bc2(float s){ v2f r; r.x = s; r.y = s; return r; }

#if defined(__has_builtin)
#if __has_builtin(__builtin_elementwise_fma)
#define HAVE_EW_FMA 1
#endif
#endif

__device__ __forceinline__ v2f vfma(v2f a, v2f b, v2f c){
#ifdef HAVE_EW_FMA
  return __builtin_elementwise_fma(a, b, c);
#else
  v2f r; r.x = fmaf(a.x, b.x, c.x); r.y = fmaf(a.y, b.y, c.y); return r;
#endif
}

// DPP: quad_perm uniform selectors (direction-proof) and row_ror:4k whose
// direction is resolved by a runtime probe.
template<int C>
__device__ __forceinline__ float dppf(float x){
  return __int_as_float(__builtin_amdgcn_update_dpp(0, __float_as_int(x), C, 0xF, 0xF, true));
}
template<int C>
__device__ __forceinline__ int dppi(int x){
  return __builtin_amdgcn_update_dpp(0, x, C, 0xF, 0xF, true);
}

template<int N> struct IC { static constexpr int v = N; };

// ============================================================
// Kernel 1: layer-0 input projection for both phases.
// P[ph][e][t][32], pos(r) = (gate*4 + (j&3))*2 + (j>>2), value includes bias.
// Wave: lanes 0-31 = encoder rows, lanes 32-63 = decoder rows; x row is a
// wave-uniform broadcast load. 4096 waves, 128 contiguous rows each.
// ============================================================
__global__ __launch_bounds__(256) void proj_kernel(
    const float* __restrict__ x,
    const float* __restrict__ eWih0, const float* __restrict__ eBih, const float* __restrict__ eBhh,
    const float* __restrict__ dWih0, const float* __restrict__ dBih, const float* __restrict__ dBhh,
    float* __restrict__ P)
{
  const int tid  = threadIdx.x;
  const int wid  = blockIdx.x * 4 + (tid >> 6);
  const int lane = tid & 63;
  const int ph   = lane >> 5;
  const int r    = lane & 31;
  const float* W = ph ? dWih0 : eWih0;
  const float b0 = ph ? (dBih[r] + dBhh[r]) : (eBih[r] + eBhh[r]);
  const int gate = r >> 3, j = r & 7;
  const int pos  = (gate * 4 + (j & 3)) * 2 + (j >> 2);

  float Wx[64];
#pragma unroll
  for (int k = 0; k < 16; ++k) {
    float4 wq = *(const float4*)(W + r * 64 + k * 4);
    Wx[k*4+0] = wq.x; Wx[k*4+1] = wq.y; Wx[k*4+2] = wq.z; Wx[k*4+3] = wq.w;
  }

  const int r0 = wid * 128;          // 4096 waves x 128 rows = 524288 = BB*TT
#pragma unroll 2
  for (int row = r0; row < r0 + 128; ++row) {
    const float* xr = x + (size_t)row * 64;
    float a0 = b0, a1 = 0.f, a2 = 0.f, a3 = 0.f;
#pragma unroll
    for (int kc = 0; kc < 16; ++kc) {
      float4 xq = *(const float4*)(xr + kc * 4);
      a0 = fmaf(Wx[kc*4+0], xq.x, a0);
      a1 = fmaf(Wx[kc*4+1], xq.y, a1);
      a2 = fmaf(Wx[kc*4+2], xq.z, a2);
      a3 = fmaf(Wx[kc*4+3], xq.w, a3);
    }
    const int e = row >> 9, t = row & 511;
    P[((size_t)((ph << 10) + e) * TT + t) * 32 + pos] = (a0 + a1) + (a2 + a3);
  }
}

// ============================================================
// Kernel 2: recurrence. 256 blocks x 64 threads; each wave = 4 batch
// elements, 16 lanes each (u = L>>2 unit-quad, g = L&3 torch gate).
// Slot pair (unit u, unit u+4) packed in v2f. No LDS, no barriers;
// P prefetched PF steps ahead in registers.
// ============================================================
__global__ __launch_bounds__(64) void recur_kernel(
    const float* __restrict__ P,
    const float* __restrict__ h0,    const float* __restrict__ c0,
    const float* __restrict__ eWihR, const float* __restrict__ eWhh,
    const float* __restrict__ eBih,  const float* __restrict__ eBhh,
    const float* __restrict__ dWihR, const float* __restrict__ dWhh,
    const float* __restrict__ dBih,  const float* __restrict__ dBhh,
    const float* __restrict__ linW,  const float* __restrict__ linB,
    float* __restrict__ out)
{
  const int lane = threadIdx.x;
  const int row  = lane >> 4;
  const int L    = lane & 15;
  const int u    = L >> 2;
  const int g    = L & 3;
  const int e    = blockIdx.x * 4 + row;

  const bool is_tanh = (g == 2);
  const float ns_act = is_tanh ? -2.885390082f : -1.44269504f;
  const float a_act  = is_tanh ? 2.0f : 1.0f;
  const float b_act  = is_tanh ? -1.0f : 0.0f;

  // runtime direction probe for row_ror:4 (wave-uniform d = 1 or 3)
  const int p4 = dppi<0x124>(u);
  const int d  = __builtin_amdgcn_readfirstlane((p4 - u) & 3);

  v2f H[3], cs[3], sd[3];
  v2f bd1 = bc2(0.f), bd2 = bc2(0.f);
  v2f WS[3][8], WB[2][8], Bss[2];

#pragma unroll
  for (int l = 0; l < 3; ++l) {
    H[l].x  = h0[((size_t)l * BB + e) * HH + u];
    H[l].y  = h0[((size_t)l * BB + e) * HH + u + 4];
    cs[l].x = c0[((size_t)l * BB + e) * HH + u];
    cs[l].y = c0[((size_t)l * BB + e) * HH + u + 4];
  }

  auto load_phase = [&](const float* WihR, const float* Whh,
                        const float* Bih, const float* Bhh) {
#pragma unroll
    for (int l = 0; l < 3; ++l) {
      const int r0 = l * 32 + g * 8 + u;
#pragma unroll
      for (int k = 0; k < 4; ++k) {
        const int col = (u + d * k) & 3;
        WS[l][k].x     = Whh[r0 * 8 + col];
        WS[l][k].y     = Whh[(r0 + 4) * 8 + col];
        WS[l][4 + k].x = Whh[r0 * 8 + 4 + col];
        WS[l][4 + k].y = Whh[(r0 + 4) * 8 + 4 + col];
      }
    }
#pragma unroll
    for (int l = 0; l < 2; ++l) {
      const int r0 = l * 32 + g * 8 + u;
#pragma unroll
      for (int k = 0; k < 4; ++k) {
        const int col = (u + d * k) & 3;
        WB[l][k].x     = WihR[r0 * 8 + col];
        WB[l][k].y     = WihR[(r0 + 4) * 8 + col];
        WB[l][4 + k].x = WihR[r0 * 8 + 4 + col];
        WB[l][4 + k].y = WihR[(r0 + 4) * 8 + 4 + col];
      }
      Bss[l].x = Bih[(l + 1) * 32 + g * 8 + u]     + Bhh[(l + 1) * 32 + g * 8 + u];
      Bss[l].y = Bih[(l + 1) * 32 + g * 8 + u + 4] + Bhh[(l + 1) * 32 + g * 8 + u + 4];
    }
    // self-dots from current h (layer-0 bias lives inside P)
#pragma unroll
    for (int l = 0; l < 3; ++l) {
      float A0[4], B0[4];
      A0[0] = H[l].x; A0[1] = dppf<0x124>(H[l].x); A0[2] = dppf<0x128>(H[l].x); A0[3] = dppf<0x12C>(H[l].x);
      B0[0] = H[l].y; B0[1] = dppf<0x124>(H[l].y); B0[2] = dppf<0x128>(H[l].y); B0[3] = dppf<0x12C>(H[l].y);
      v2f acc = bc2(0.f);
      if (l) acc = Bss[l - 1];
#pragma unroll
      for (int k = 0; k < 4; ++k) {
        acc = vfma(WS[l][k],     bc2(A0[k]), acc);
        acc = vfma(WS[l][4 + k], bc2(B0[k]), acc);
      }
      sd[l] = acc;
    }
  };

  // one packed LSTM cell step for layer l; returns below-dot for layer l+1
  auto lstep = [&](auto LC, v2f in) -> v2f {
    constexpr int l = decltype(LC)::v;
    v2f pre = in + sd[l];
    v2f ex; ex.x = fexp2(ns_act * pre.x); ex.y = fexp2(ns_act * pre.y);
    v2f rc; rc.x = frcp(1.f + ex.x);      rc.y = frcp(1.f + ex.y);
    v2f act = vfma(bc2(a_act), rc, bc2(b_act));
    v2f Gi, Gf, Gg, Go;
    Gi.x = dppf<0x00>(act.x); Gi.y = dppf<0x00>(act.y);
    Gf.x = dppf<0x55>(act.x); Gf.y = dppf<0x55>(act.y);
    Gg.x = dppf<0xAA>(act.x); Gg.y = dppf<0xAA>(act.y);
    Go.x = dppf<0xFF>(act.x); Go.y = dppf<0xFF>(act.y);
    v2f cn = vfma(Gf, cs[l], Gi * Gg);
    cs[l] = cn;
    v2f tx; tx.x = fexp2(-2.885390082f * cn.x); tx.y = fexp2(-2.885390082f * cn.y);
    v2f tr; tr.x = frcp(1.f + tx.x);            tr.y = frcp(1.f + tx.y);
    v2f th = vfma(bc2(2.f), tr, bc2(-1.f));
    v2f hn = Go * th;
    H[l] = hn;
    float A0[4], B0[4];
    A0[0] = hn.x; A0[1] = dppf<0x124>(hn.x); A0[2] = dppf<0x128>(hn.x); A0[3] = dppf<0x12C>(hn.x);
    B0[0] = hn.y; B0[1] = dppf<0x124>(hn.y); B0[2] = dppf<0x128>(hn.y); B0[3] = dppf<0x12C>(hn.y);
    v2f accS;
    if constexpr (l > 0) accS = Bss[l - 1]; else accS = bc2(0.f);
    v2f accB = bc2(0.f);
#pragma unroll
    for (int k = 0; k < 4; ++k) {
      accS = vfma(WS[l][k],     bc2(A0[k]), accS);
      accS = vfma(WS[l][4 + k], bc2(B0[k]), accS);
      if constexpr (l < 2) {
        accB = vfma(WB[l][k],     bc2(A0[k]), accB);
        accB = vfma(WB[l][4 + k], bc2(B0[k]), accB);
      }
    }
    sd[l] = accS;
    return accB;
  };

#pragma unroll 1
  for (int ph = 0; ph < 2; ++ph) {
    if (ph == 0) load_phase(eWihR, eWhh, eBih, eBhh);
    else         load_phase(dWihR, dWhh, dBih, dBhh);

    const float* Pb = P + ((size_t)((ph << 10) + e) * TT) * 32 + (g * 4 + u) * 2;

    // fill prefetch pipeline with steps 0..PF-1
    v2f pf[PF];
#pragma unroll
    for (int k = 0; k < PF; ++k) pf[k] = *(const v2f*)(Pb + k * 32);

    // peeled group t = 0..7 (skew startup), refill t = 8..15
#pragma unroll
    for (int k = 0; k < PF; ++k) {
      v2f cur = pf[k];
      pf[k] = *(const v2f*)(Pb + (k + PF) * 32);
      v2f n1 = lstep(IC<0>{}, cur);
      v2f n2 = bc2(0.f);
      if (k >= 1) n2 = lstep(IC<1>{}, bd1);
      if (k >= 2) (void)lstep(IC<2>{}, bd2);
      bd1 = n1; bd2 = n2;
    }

    // main loop t = 8..511, branch-free
#pragma unroll 1
    for (int t = PF; t < TT; t += PF) {
#pragma unroll
      for (int k = 0; k < PF; ++k) {
        v2f cur = pf[k];
        int tn = t + k + PF; if (tn > TT - 1) tn = TT - 1;
        pf[k] = *(const v2f*)(Pb + tn * 32);
        v2f n1 = lstep(IC<0>{}, cur);
        v2f n2 = lstep(IC<1>{}, bd1);
        (void)lstep(IC<2>{}, bd2);
        bd1 = n1; bd2 = n2;
      }
    }

    // drain skew: layer1 t=511, layer2 t=510, layer2 t=511
    v2f dd = lstep(IC<1>{}, bd1);
    (void)lstep(IC<2>{}, bd2);
    (void)lstep(IC<2>{}, dd);
  }

  // epilogue: linear on final decoder layer-2 h
  float lwA[4], lwB[4];
#pragma unroll
  for (int k = 0; k < 4; ++k) {
    const int col = (u + d * k) & 3;
    lwA[k] = linW[col];
    lwB[k] = linW[4 + col];
  }
  float A0[4], B0[4];
  A0[0] = H[2].x; A0[1] = dppf<0x124>(H[2].x); A0[2] = dppf<0x128>(H[2].x); A0[3] = dppf<0x12C>(H[2].x);
  B0[0] = H[2].y; B0[1] = dppf<0x124>(H[2].y); B0[2] = dppf<0x128>(H[2].y); B0[3] = dppf<0x12C>(H[2].y);
  float pred = linB[0];
#pragma unroll
  for (int k = 0; k < 4; ++k) {
    pred = fmaf(lwA[k], A0[k], pred);
    pred = fmaf(lwB[k], B0[k], pred);
  }
  if (L == 0) out[e] = pred;
}

// ============================================================
// Fallback (ws too small): round-1 verified single-kernel version.
// ============================================================
__global__ __launch_bounds__(64) void seq2seq_fallback(
    const float* __restrict__ x, const float* __restrict__ h0, const float* __restrict__ c0,
    const float* __restrict__ eWih0, const float* __restrict__ eWihR, const float* __restrict__ eWhh,
    const float* __restrict__ eBih,  const float* __restrict__ eBhh,
    const float* __restrict__ dWih0, const float* __restrict__ dWihR, const float* __restrict__ dWhh,
    const float* __restrict__ dBih,  const float* __restrict__ dBhh,
    const float* __restrict__ linW,  const float* __restrict__ linB, float* __restrict__ out)
{
  const int tid = threadIdx.x;
  const int g   = tid & 31;
  const int grp = tid & 32;
  const int jj  = g & 7;
  const int e   = blockIdx.x * 2 + (tid >> 5);
  const bool is_tanh = ((g >> 3) == 2);
  const float s_act = is_tanh ? 2.885390082f : 1.44269504f;
  const float a_act = is_tanh ? 2.0f : 1.0f;
  const float b_act = is_tanh ? -1.0f : 0.0f;
  float hrep[3][8]; float cc[3];
#pragma unroll
  for (int l = 0; l < 3; ++l) {
#pragma unroll
    for (int k = 0; k < 8; ++k) hrep[l][k] = h0[((size_t)l * BB + e) * HH + k];
    cc[l] = c0[((size_t)l * BB + e) * HH + jj];
  }
  for (int p = 0; p < 2; ++p) {
    const float* Wih0 = p ? dWih0 : eWih0;  const float* WihR = p ? dWihR : eWihR;
    const float* Whh  = p ? dWhh  : eWhh;   const float* Bih  = p ? dBih  : eBih;
    const float* Bhh  = p ? dBhh  : eBhh;
    float Wx[64];
#pragma unroll
    for (int k = 0; k < 64; k += 4) {
      float4 w = *(const float4*)(Wih0 + g * 64 + k);
      Wx[k] = w.x; Wx[k+1] = w.y; Wx[k+2] = w.z; Wx[k+3] = w.w;
    }
    float Wh[3][8], Wi[2][8], bias[3];
#pragma unroll
    for (int l = 0; l < 3; ++l) {
#pragma unroll
      for (int k = 0; k < 8; ++k) Wh[l][k] = Whh[(l*32+g)*8+k];
      bias[l] = Bih[l*32+g] + Bhh[l*32+g];
    }
#pragma unroll
    for (int l = 0; l < 2; ++l)
#pragma unroll
      for (int k = 0; k < 8; ++k) Wi[l][k] = WihR[(l*32+g)*8+k];
    const float* xrow = x + (size_t)e * TT * DD;
    for (int t = 0; t < TT; ++t) {
      float4 acc = make_float4(bias[0], 0.f, 0.f, 0.f);
#pragma unroll
      for (int kc = 0; kc < 16; ++kc) {
        float4 xv = *(const float4*)(xrow + kc * 4);
        acc.x = fmaf(Wx[kc*4+0], xv.x, acc.x); acc.y = fmaf(Wx[kc*4+1], xv.y, acc.y);
        acc.z = fmaf(Wx[kc*4+2], xv.z, acc.z); acc.w = fmaf(Wx[kc*4+3], xv.w, acc.w);
      }
      float pre = (acc.x + acc.y) + (acc.z + acc.w);
      { float r0=0.f,r1=0.f;
#pragma unroll
        for (int k = 0; k < 8; k += 2) { r0=fmaf(Wh[0][k],hrep[0][k],r0); r1=fmaf(Wh[0][k+1],hrep[0][k+1],r1); }
        pre += r0 + r1; }
#pragma unroll
      for (int l = 0; l < 3; ++l) {
        if (l > 0) {
          float r0 = bias[l], r1 = 0.f;
#pragma unroll
          for (int k = 0; k < 8; k += 2) {
            r0=fmaf(Wi[l-1][k],hrep[l-1][k],r0); r1=fmaf(Wi[l-1][k+1],hrep[l-1][k+1],r1);
            r0=fmaf(Wh[l][k],hrep[l][k],r0);     r1=fmaf(Wh[l][k+1],hrep[l][k+1],r1);
          }
          pre = r0 + r1;
        }
        float act = fmaf(a_act, frcp(1.0f + fexp2(-s_act * pre)), b_act);
        float iv = __shfl(act, grp + jj);
        float fv = __shfl(act, grp + 8 + jj);
        float gv = __shfl(act, grp + 16 + jj);
        float ov = __shfl(act, grp + 24 + jj);
        float cn = fmaf(fv, cc[l], iv * gv);
        cc[l] = cn;
        float th = fmaf(2.0f, frcp(1.0f + fexp2(-2.885390082f * cn)), -1.0f);
        float hn = ov * th;
#pragma unroll
        for (int k = 0; k < 8; ++k) hrep[l][k] = __shfl(hn, grp + k);
      }
      xrow += DD;
    }
  }
  float pred = linB[0];
#pragma unroll
  for (int k = 0; k < 8; ++k) pred = fmaf(linW[k], hrep[2][k], pred);
  if (g == 0) out[e] = pred;
}

extern "C" void kernel_launch(void* const* d_in, const int* in_sizes, int n_in,
                              void* d_out, int out_size, void* d_ws, size_t ws_size,
                              hipStream_t stream) {
  const float* x     = (const float*)d_in[0];
  const float* h0    = (const float*)d_in[1];
  const float* c0    = (const float*)d_in[2];
  const float* eWih0 = (const float*)d_in[3];
  const float* eWihR = (const float*)d_in[4];
  const float* eWhh  = (const float*)d_in[5];
  const float* eBih  = (const float*)d_in[6];
  const float* eBhh  = (const float*)d_in[7];
  const float* dWih0 = (const float*)d_in[8];
  const float* dWihR = (const float*)d_in[9];
  const float* dWhh  = (const float*)d_in[10];
  const float* dBih  = (const float*)d_in[11];
  const float* dBhh  = (const float*)d_in[12];
  const float* linW  = (const float*)d_in[13];
  const float* linB  = (const float*)d_in[14];
  float* out = (float*)d_out;

  const size_t P_BYTES = (size_t)2 * BB * TT * 32 * sizeof(float);  // 128 MiB
  if (ws_size >= P_BYTES) {
    float* P = (float*)d_ws;
    proj_kernel<<<1024, 256, 0, stream>>>(x, eWih0, eBih, eBhh, dWih0, dBih, dBhh, P);
    recur_kernel<<<BB / 4, 64, 0, stream>>>(P, h0, c0, eWihR, eWhh, eBih, eBhh,
                                            dWihR, dWhh, dBih, dBhh, linW, linB, out);
  } else {
    seq2seq_fallback<<<BB / 2, 64, 0, stream>>>(x, h0, c0, eWih0, eWihR, eWhh, eBih, eBhh,
                                                dWih0, dWihR, dWhh, dBih, dBhh, linW, linB, out);
  }
}

// Round 7
// 648.240 us; speedup vs baseline: 1.4484x; 1.4484x over previous
//
#include <hip/hip_runtime.h>

#define TT 512
#define DD 64
#define BB 1024
#define PF 8               // prefetch depth (steps) in the recurrence
#define HH 8

typedef float v2f __attribute__((ext_vector_type(2)));

__device__ __forceinline__ float fexp2(float x){ return __builtin_amdgcn_exp2f(x); }
__device__ __forceinline__ float frcp (float x){ return __builtin_amdgcn_rcpf(x); }

__device__ __forceinline__ v2f bc2(float s){ v2f r; r.x = s; r.y = s; return r; }

#if defined(__has_builtin)
#if __has_builtin(__builtin_elementwise_fma)
#define HAVE_EW_FMA 1
#endif
#endif

__device__ __forceinline__ v2f vfma(v2f a, v2f b, v2f c){
#ifdef HAVE_EW_FMA
  return __builtin_elementwise_fma(a, b, c);
#else
  v2f r; r.x = fmaf(a.x, b.x, c.x); r.y = fmaf(a.y, b.y, c.y); return r;
#endif
}

// DPP: quad_perm uniform selectors (direction-proof) and row_ror:4k whose
// direction is resolved by a runtime probe.
template<int C>
__device__ __forceinline__ float dppf(float x){
  return __int_as_float(__builtin_amdgcn_update_dpp(0, __float_as_int(x), C, 0xF, 0xF, true));
}
template<int C>
__device__ __forceinline__ int dppi(int x){
  return __builtin_amdgcn_update_dpp(0, x, C, 0xF, 0xF, true);
}

template<int N> struct IC { static constexpr int v = N; };

// ============================================================
// Kernel 1 (v2): layer-0 input projection for both phases.
// P[ph][e][t][32], pos(r) = (gate*4 + (j&3))*2 + (j>>2), value includes bias.
// 2048 blocks x 256 threads. Each wave owns 64 consecutive x-rows, processed
// as 4 groups of 16 rows through a wave-private double-buffered LDS tile:
//   - global loads: per-lane coalesced float4, issued one group ahead
//   - compute: per row, 16 broadcast ds_read_b128 + 64 FMA; lane c in [0,64)
//     computes output column c (c<32: encoder row c; c>=32: decoder row c-32)
// No __syncthreads: each wave reads only its own staging region.
// ============================================================
__global__ __launch_bounds__(256) void proj_kernel(
    const float* __restrict__ x,
    const float* __restrict__ eWih0, const float* __restrict__ eBih, const float* __restrict__ eBhh,
    const float* __restrict__ dWih0, const float* __restrict__ dBih, const float* __restrict__ dBhh,
    float* __restrict__ P)
{
  __shared__ __align__(16) float xs[4][2][16 * 64];   // [wave][buf][row*64+k] = 32 KiB
  const int tid  = threadIdx.x;
  const int w    = tid >> 6;
  const int lane = tid & 63;
  const int ph   = lane >> 5;
  const int r    = lane & 31;
  const float* W = ph ? dWih0 : eWih0;
  const float b0 = ph ? (dBih[r] + dBhh[r]) : (eBih[r] + eBhh[r]);
  const int gate = r >> 3, j = r & 7;
  const int pos  = (gate * 4 + (j & 3)) * 2 + (j >> 2);

  float Wx[64];
#pragma unroll
  for (int k = 0; k < 16; ++k) {
    float4 wq = *(const float4*)(W + r * 64 + k * 4);
    Wx[k*4+0] = wq.x; Wx[k*4+1] = wq.y; Wx[k*4+2] = wq.z; Wx[k*4+3] = wq.w;
  }

  const int base_row = (blockIdx.x * 4 + w) * 64;     // 8192 waves x 64 rows
  const float* xg = x + (size_t)base_row * 64;

  float4 st[4];
  // stage group 0 into buf 0
#pragma unroll
  for (int i = 0; i < 4; ++i) st[i] = *(const float4*)(xg + i * 256 + lane * 4);
#pragma unroll
  for (int i = 0; i < 4; ++i) *(float4*)&xs[w][0][i * 256 + lane * 4] = st[i];
  // issue loads for group 1
#pragma unroll
  for (int i = 0; i < 4; ++i) st[i] = *(const float4*)(xg + 1024 + i * 256 + lane * 4);

#pragma unroll 1
  for (int g = 0; g < 4; ++g) {
    const float* buf = &xs[w][g & 1][0];
#pragma unroll 2
    for (int ri = 0; ri < 16; ++ri) {
      float a0 = b0, a1 = 0.f, a2 = 0.f, a3 = 0.f;
#pragma unroll
      for (int kc = 0; kc < 16; ++kc) {
        float4 xv = *(const float4*)(buf + ri * 64 + kc * 4);
        a0 = fmaf(Wx[kc*4+0], xv.x, a0);
        a1 = fmaf(Wx[kc*4+1], xv.y, a1);
        a2 = fmaf(Wx[kc*4+2], xv.z, a2);
        a3 = fmaf(Wx[kc*4+3], xv.w, a3);
      }
      const int row = base_row + g * 16 + ri;
      const int e = row >> 9, t = row & 511;
      P[((size_t)((ph << 10) + e) * TT + t) * 32 + pos] = (a0 + a1) + (a2 + a3);
    }
    if (g < 3) {
      // commit staged group g+1 (waits vmcnt for st automatically)
#pragma unroll
      for (int i = 0; i < 4; ++i) *(float4*)&xs[w][(g + 1) & 1][i * 256 + lane * 4] = st[i];
      if (g < 2) {
        // issue loads for group g+2
#pragma unroll
        for (int i = 0; i < 4; ++i)
          st[i] = *(const float4*)(xg + (size_t)(g + 2) * 1024 + i * 256 + lane * 4);
      }
    }
  }
}

// ============================================================
// Kernel 2: recurrence (UNCHANGED from round 6 — verified absmax 0.0).
// 256 blocks x 64 threads; each wave = 4 batch elements, 16 lanes each
// (u = L>>2 unit-quad, g = L&3 torch gate). Slot pair (u, u+4) packed in v2f.
// No LDS, no barriers; P prefetched PF steps ahead in registers.
// ============================================================
__global__ __launch_bounds__(64) void recur_kernel(
    const float* __restrict__ P,
    const float* __restrict__ h0,    const float* __restrict__ c0,
    const float* __restrict__ eWihR, const float* __restrict__ eWhh,
    const float* __restrict__ eBih,  const float* __restrict__ eBhh,
    const float* __restrict__ dWihR, const float* __restrict__ dWhh,
    const float* __restrict__ dBih,  const float* __restrict__ dBhh,
    const float* __restrict__ linW,  const float* __restrict__ linB,
    float* __restrict__ out)
{
  const int lane = threadIdx.x;
  const int row  = lane >> 4;
  const int L    = lane & 15;
  const int u    = L >> 2;
  const int g    = L & 3;
  const int e    = blockIdx.x * 4 + row;

  const bool is_tanh = (g == 2);
  const float ns_act = is_tanh ? -2.885390082f : -1.44269504f;
  const float a_act  = is_tanh ? 2.0f : 1.0f;
  const float b_act  = is_tanh ? -1.0f : 0.0f;

  // runtime direction probe for row_ror:4 (wave-uniform d = 1 or 3)
  const int p4 = dppi<0x124>(u);
  const int d  = __builtin_amdgcn_readfirstlane((p4 - u) & 3);

  v2f H[3], cs[3], sd[3];
  v2f bd1 = bc2(0.f), bd2 = bc2(0.f);
  v2f WS[3][8], WB[2][8], Bss[2];

#pragma unroll
  for (int l = 0; l < 3; ++l) {
    H[l].x  = h0[((size_t)l * BB + e) * HH + u];
    H[l].y  = h0[((size_t)l * BB + e) * HH + u + 4];
    cs[l].x = c0[((size_t)l * BB + e) * HH + u];
    cs[l].y = c0[((size_t)l * BB + e) * HH + u + 4];
  }

  auto load_phase = [&](const float* WihR, const float* Whh,
                        const float* Bih, const float* Bhh) {
#pragma unroll
    for (int l = 0; l < 3; ++l) {
      const int r0 = l * 32 + g * 8 + u;
#pragma unroll
      for (int k = 0; k < 4; ++k) {
        const int col = (u + d * k) & 3;
        WS[l][k].x     = Whh[r0 * 8 + col];
        WS[l][k].y     = Whh[(r0 + 4) * 8 + col];
        WS[l][4 + k].x = Whh[r0 * 8 + 4 + col];
        WS[l][4 + k].y = Whh[(r0 + 4) * 8 + 4 + col];
      }
    }
#pragma unroll
    for (int l = 0; l < 2; ++l) {
      const int r0 = l * 32 + g * 8 + u;
#pragma unroll
      for (int k = 0; k < 4; ++k) {
        const int col = (u + d * k) & 3;
        WB[l][k].x     = WihR[r0 * 8 + col];
        WB[l][k].y     = WihR[(r0 + 4) * 8 + col];
        WB[l][4 + k].x = WihR[r0 * 8 + 4 + col];
        WB[l][4 + k].y = WihR[(r0 + 4) * 8 + 4 + col];
      }
      Bss[l].x = Bih[(l + 1) * 32 + g * 8 + u]     + Bhh[(l + 1) * 32 + g * 8 + u];
      Bss[l].y = Bih[(l + 1) * 32 + g * 8 + u + 4] + Bhh[(l + 1) * 32 + g * 8 + u + 4];
    }
    // self-dots from current h (layer-0 bias lives inside P)
#pragma unroll
    for (int l = 0; l < 3; ++l) {
      float A0[4], B0[4];
      A0[0] = H[l].x; A0[1] = dppf<0x124>(H[l].x); A0[2] = dppf<0x128>(H[l].x); A0[3] = dppf<0x12C>(H[l].x);
      B0[0] = H[l].y; B0[1] = dppf<0x124>(H[l].y); B0[2] = dppf<0x128>(H[l].y); B0[3] = dppf<0x12C>(H[l].y);
      v2f acc = bc2(0.f);
      if (l) acc = Bss[l - 1];
#pragma unroll
      for (int k = 0; k < 4; ++k) {
        acc = vfma(WS[l][k],     bc2(A0[k]), acc);
        acc = vfma(WS[l][4 + k], bc2(B0[k]), acc);
      }
      sd[l] = acc;
    }
  };

  // one packed LSTM cell step for layer l; returns below-dot for layer l+1
  auto lstep = [&](auto LC, v2f in) -> v2f {
    constexpr int l = decltype(LC)::v;
    v2f pre = in + sd[l];
    v2f ex; ex.x = fexp2(ns_act * pre.x); ex.y = fexp2(ns_act * pre.y);
    v2f rc; rc.x = frcp(1.f + ex.x);      rc.y = frcp(1.f + ex.y);
    v2f act = vfma(bc2(a_act), rc, bc2(b_act));
    v2f Gi, Gf, Gg, Go;
    Gi.x = dppf<0x00>(act.x); Gi.y = dppf<0x00>(act.y);
    Gf.x = dppf<0x55>(act.x); Gf.y = dppf<0x55>(act.y);
    Gg.x = dppf<0xAA>(act.x); Gg.y = dppf<0xAA>(act.y);
    Go.x = dppf<0xFF>(act.x); Go.y = dppf<0xFF>(act.y);
    v2f cn = vfma(Gf, cs[l], Gi * Gg);
    cs[l] = cn;
    v2f tx; tx.x = fexp2(-2.885390082f * cn.x); tx.y = fexp2(-2.885390082f * cn.y);
    v2f tr; tr.x = frcp(1.f + tx.x);            tr.y = frcp(1.f + tx.y);
    v2f th = vfma(bc2(2.f), tr, bc2(-1.f));
    v2f hn = Go * th;
    H[l] = hn;
    float A0[4], B0[4];
    A0[0] = hn.x; A0[1] = dppf<0x124>(hn.x); A0[2] = dppf<0x128>(hn.x); A0[3] = dppf<0x12C>(hn.x);
    B0[0] = hn.y; B0[1] = dppf<0x124>(hn.y); B0[2] = dppf<0x128>(hn.y); B0[3] = dppf<0x12C>(hn.y);
    v2f accS;
    if constexpr (l > 0) accS = Bss[l - 1]; else accS = bc2(0.f);
    v2f accB = bc2(0.f);
#pragma unroll
    for (int k = 0; k < 4; ++k) {
      accS = vfma(WS[l][k],     bc2(A0[k]), accS);
      accS = vfma(WS[l][4 + k], bc2(B0[k]), accS);
      if constexpr (l < 2) {
        accB = vfma(WB[l][k],     bc2(A0[k]), accB);
        accB = vfma(WB[l][4 + k], bc2(B0[k]), accB);
      }
    }
    sd[l] = accS;
    return accB;
  };

#pragma unroll 1
  for (int ph = 0; ph < 2; ++ph) {
    if (ph == 0) load_phase(eWihR, eWhh, eBih, eBhh);
    else         load_phase(dWihR, dWhh, dBih, dBhh);

    const float* Pb = P + ((size_t)((ph << 10) + e) * TT) * 32 + (g * 4 + u) * 2;

    // fill prefetch pipeline with steps 0..PF-1
    v2f pf[PF];
#pragma unroll
    for (int k = 0; k < PF; ++k) pf[k] = *(const v2f*)(Pb + k * 32);

    // peeled group t = 0..7 (skew startup), refill t = 8..15
#pragma unroll
    for (int k = 0; k < PF; ++k) {
      v2f cur = pf[k];
      pf[k] = *(const v2f*)(Pb + (k + PF) * 32);
      v2f n1 = lstep(IC<0>{}, cur);
      v2f n2 = bc2(0.f);
      if (k >= 1) n2 = lstep(IC<1>{}, bd1);
      if (k >= 2) (void)lstep(IC<2>{}, bd2);
      bd1 = n1; bd2 = n2;
    }

    // main loop t = 8..511, branch-free
#pragma unroll 1
    for (int t = PF; t < TT; t += PF) {
#pragma unroll
      for (int k = 0; k < PF; ++k) {
        v2f cur = pf[k];
        int tn = t + k + PF; if (tn > TT - 1) tn = TT - 1;
        pf[k] = *(const v2f*)(Pb + tn * 32);
        v2f n1 = lstep(IC<0>{}, cur);
        v2f n2 = lstep(IC<1>{}, bd1);
        (void)lstep(IC<2>{}, bd2);
        bd1 = n1; bd2 = n2;
      }
    }

    // drain skew: layer1 t=511, layer2 t=510, layer2 t=511
    v2f dd = lstep(IC<1>{}, bd1);
    (void)lstep(IC<2>{}, bd2);
    (void)lstep(IC<2>{}, dd);
  }

  // epilogue: linear on final decoder layer-2 h
  float lwA[4], lwB[4];
#pragma unroll
  for (int k = 0; k < 4; ++k) {
    const int col = (u + d * k) & 3;
    lwA[k] = linW[col];
    lwB[k] = linW[4 + col];
  }
  float A0[4], B0[4];
  A0[0] = H[2].x; A0[1] = dppf<0x124>(H[2].x); A0[2] = dppf<0x128>(H[2].x); A0[3] = dppf<0x12C>(H[2].x);
  B0[0] = H[2].y; B0[1] = dppf<0x124>(H[2].y); B0[2] = dppf<0x128>(H[2].y); B0[3] = dppf<0x12C>(H[2].y);
  float pred = linB[0];
#pragma unroll
  for (int k = 0; k < 4; ++k) {
    pred = fmaf(lwA[k], A0[k], pred);
    pred = fmaf(lwB[k], B0[k], pred);
  }
  if (L == 0) out[e] = pred;
}

// ============================================================
// Fallback (ws too small): round-1 verified single-kernel version.
// ============================================================
__global__ __launch_bounds__(64) void seq2seq_fallback(
    const float* __restrict__ x, const float* __restrict__ h0, const float* __restrict__ c0,
    const float* __restrict__ eWih0, const float* __restrict__ eWihR, const float* __restrict__ eWhh,
    const float* __restrict__ eBih,  const float* __restrict__ eBhh,
    const float* __restrict__ dWih0, const float* __restrict__ dWihR, const float* __restrict__ dWhh,
    const float* __restrict__ dBih,  const float* __restrict__ dBhh,
    const float* __restrict__ linW,  const float* __restrict__ linB, float* __restrict__ out)
{
  const int tid = threadIdx.x;
  const int g   = tid & 31;
  const int grp = tid & 32;
  const int jj  = g & 7;
  const int e   = blockIdx.x * 2 + (tid >> 5);
  const bool is_tanh = ((g >> 3) == 2);
  const float s_act = is_tanh ? 2.885390082f : 1.44269504f;
  const float a_act = is_tanh ? 2.0f : 1.0f;
  const float b_act = is_tanh ? -1.0f : 0.0f;
  float hrep[3][8]; float cc[3];
#pragma unroll
  for (int l = 0; l < 3; ++l) {
#pragma unroll
    for (int k = 0; k < 8; ++k) hrep[l][k] = h0[((size_t)l * BB + e) * HH + k];
    cc[l] = c0[((size_t)l * BB + e) * HH + jj];
  }
  for (int p = 0; p < 2; ++p) {
    const float* Wih0 = p ? dWih0 : eWih0;  const float* WihR = p ? dWihR : eWihR;
    const float* Whh  = p ? dWhh  : eWhh;   const float* Bih  = p ? dBih  : eBih;
    const float* Bhh  = p ? dBhh  : eBhh;
    float Wx[64];
#pragma unroll
    for (int k = 0; k < 64; k += 4) {
      float4 w = *(const float4*)(Wih0 + g * 64 + k);
      Wx[k] = w.x; Wx[k+1] = w.y; Wx[k+2] = w.z; Wx[k+3] = w.w;
    }
    float Wh[3][8], Wi[2][8], bias[3];
#pragma unroll
    for (int l = 0; l < 3; ++l) {
#pragma unroll
      for (int k = 0; k < 8; ++k) Wh[l][k] = Whh[(l*32+g)*8+k];
      bias[l] = Bih[l*32+g] + Bhh[l*32+g];
    }
#pragma unroll
    for (int l = 0; l < 2; ++l)
#pragma unroll
      for (int k = 0; k < 8; ++k) Wi[l][k] = WihR[(l*32+g)*8+k];
    const float* xrow = x + (size_t)e * TT * DD;
    for (int t = 0; t < TT; ++t) {
      float4 acc = make_float4(bias[0], 0.f, 0.f, 0.f);
#pragma unroll
      for (int kc = 0; kc < 16; ++kc) {
        float4 xv = *(const float4*)(xrow + kc * 4);
        acc.x = fmaf(Wx[kc*4+0], xv.x, acc.x); acc.y = fmaf(Wx[kc*4+1], xv.y, acc.y);
        acc.z = fmaf(Wx[kc*4+2], xv.z, acc.z); acc.w = fmaf(Wx[kc*4+3], xv.w, acc.w);
      }
      float pre = (acc.x + acc.y) + (acc.z + acc.w);
      { float r0=0.f,r1=0.f;
#pragma unroll
        for (int k = 0; k < 8; k += 2) { r0=fmaf(Wh[0][k],hrep[0][k],r0); r1=fmaf(Wh[0][k+1],hrep[0][k+1],r1); }
        pre += r0 + r1; }
#pragma unroll
      for (int l = 0; l < 3; ++l) {
        if (l > 0) {
          float r0 = bias[l], r1 = 0.f;
#pragma unroll
          for (int k = 0; k < 8; k += 2) {
            r0=fmaf(Wi[l-1][k],hrep[l-1][k],r0); r1=fmaf(Wi[l-1][k+1],hrep[l-1][k+1],r1);
            r0=fmaf(Wh[l][k],hrep[l][k],r0);     r1=fmaf(Wh[l][k+1],hrep[l][k+1],r1);
          }
          pre = r0 + r1;
        }
        float act = fmaf(a_act, frcp(1.0f + fexp2(-s_act * pre)), b_act);
        float iv = __shfl(act, grp + jj);
        float fv = __shfl(act, grp + 8 + jj);
        float gv = __shfl(act, grp + 16 + jj);
        float ov = __shfl(act, grp + 24 + jj);
        float cn = fmaf(fv, cc[l], iv * gv);
        cc[l] = cn;
        float th = fmaf(2.0f, frcp(1.0f + fexp2(-2.885390082f * cn)), -1.0f);
        float hn = ov * th;
#pragma unroll
        for (int k = 0; k < 8; ++k) hrep[l][k] = __shfl(hn, grp + k);
      }
      xrow += DD;
    }
  }
  float pred = linB[0];
#pragma unroll
  for (int k = 0; k < 8; ++k) pred = fmaf(linW[k], hrep[2][k], pred);
  if (g == 0) out[e] = pred;
}

extern "C" void kernel_launch(void* const* d_in, const int* in_sizes, int n_in,
                              void* d_out, int out_size, void* d_ws, size_t ws_size,
                              hipStream_t stream) {
  const float* x     = (const float*)d_in[0];
  const float* h0    = (const float*)d_in[1];
  const float* c0    = (const float*)d_in[2];
  const float* eWih0 = (const float*)d_in[3];
  const float* eWihR = (const float*)d_in[4];
  const float* eWhh  = (const float*)d_in[5];
  const float* eBih  = (const float*)d_in[6];
  const float* eBhh  = (const float*)d_in[7];
  const float* dWih0 = (const float*)d_in[8];
  const float* dWihR = (const float*)d_in[9];
  const float* dWhh  = (const float*)d_in[10];
  const float* dBih  = (const float*)d_in[11];
  const float* dBhh  = (const float*)d_in[12];
  const float* linW  = (const float*)d_in[13];
  const float* linB  = (const float*)d_in[14];
  float* out = (float*)d_out;

  const size_t P_BYTES = (size_t)2 * BB * TT * 32 * sizeof(float);  // 128 MiB
  if (ws_size >= P_BYTES) {
    float* P = (float*)d_ws;
    proj_kernel<<<2048, 256, 0, stream>>>(x, eWih0, eBih, eBhh, dWih0, dBih, dBhh, P);
    recur_kernel<<<BB / 4, 64, 0, stream>>>(P, h0, c0, eWihR, eWhh, eBih, eBhh,
                                            dWihR, dWhh, dBih, dBhh, linW, linB, out);
  } else {
    seq2seq_fallback<<<BB / 2, 64, 0, stream>>>(x, h0, c0, eWih0, eWihR, eWhh, eBih, eBhh,
                                                dWih0, dWihR, dWhh, dBih, dBhh, linW, linB, out);
  }
}